// Round 4
// baseline (2734.516 us; speedup 1.0000x reference)
//
#include <hip/hip_runtime.h>
#include <hip/hip_bf16.h>
#include <stdint.h>

// ---------------------------------------------------------------------------
// Kiperwasser parser: embed -> BiLSTM(2 layers, H=256, N=512) -> pair scorer.
//   - feed-forward GEMMs via a generic tiled fp32 kernel
//   - recurrent scan: 2 blocks per direction; Whh held in 32 NAMED uint4
//     variables per thread (128 VGPRs, pinned via opaque asm on named SSA
//     values -- an array/alloca defeats promotion, see round-2/3 post-mortems
//     where VGPR_Count stayed 84 and weights streamed from L2 every step),
//     dot via v_dot2_f32_f16; h halves exchanged between partner blocks
//     through sentinel-initialized global slots (relaxed atomics, 1 L3 trip)
// ---------------------------------------------------------------------------

typedef _Float16 f16x2 __attribute__((ext_vector_type(2)));

#define SCOPE_AGENT __HIP_MEMORY_SCOPE_AGENT
constexpr uint32_t SENT = 0x7FFF7FFFu;  // f16 NaN pair: unreachable as packed h

__device__ __forceinline__ float fdot2f(uint32_t w, uint32_t h, float acc) {
#if __has_builtin(__builtin_amdgcn_fdot2)
  return __builtin_amdgcn_fdot2(__builtin_bit_cast(f16x2, w),
                                __builtin_bit_cast(f16x2, h), acc, false);
#else
  f16x2 a = __builtin_bit_cast(f16x2, w);
  f16x2 b = __builtin_bit_cast(f16x2, h);
  return acc + (float)a.x * (float)b.x + (float)a.y * (float)b.y;
#endif
}

__device__ __forceinline__ float fsigm(float x) { return 1.f / (1.f + __expf(-x)); }
__device__ __forceinline__ float ftanh(float x) {
  float e = __expf(2.f * x);
  return 1.f - 2.f / (e + 1.f);
}

// ---------------- workspace layout (bytes) ----------------
constexpr size_t ALN(size_t x) { return (x + 1023) & ~(size_t)1023; }
constexpr size_t O_EX    = 0;                       // 4(ld) * 512 * 128 u32 = 1 MB
constexpr size_t SZ_EX   = 4ull * 512 * 128 * 4;
constexpr size_t O_WPK   = ALN(O_EX + SZ_EX);       // 4(ld) * 32chunk * 1024owner * uint4 = 2 MB
constexpr size_t SZ_WPK  = 4ull * 128 * 1024 * 4;
constexpr size_t O_X0    = ALN(O_WPK + SZ_WPK);     // 512 x 125 f32
constexpr size_t SZ_X0   = 512ull * 125 * 4;
constexpr size_t O_WTIH0 = ALN(O_X0 + SZ_X0);       // 2 x [128][1024]
constexpr size_t SZ_WTIH0 = 2ull * 128 * 1024 * 4;
constexpr size_t O_WTIH1 = ALN(O_WTIH0 + SZ_WTIH0); // 2 x [512][1024]
constexpr size_t SZ_WTIH1 = 2ull * 512 * 1024 * 4;
constexpr size_t O_WTA   = ALN(O_WTIH1 + SZ_WTIH1); // [512][100]
constexpr size_t SZ_WTAB = 512ull * 100 * 4;
constexpr size_t O_WTB   = ALN(O_WTA + SZ_WTAB);    // [512][100]
constexpr size_t O_PRE0  = ALN(O_WTB + SZ_WTAB);    // 2 x [512][1024]
constexpr size_t SZ_PRE  = 2ull * 512 * 1024 * 4;
constexpr size_t O_PRE1  = ALN(O_PRE0 + SZ_PRE);
constexpr size_t O_H0    = ALN(O_PRE1 + SZ_PRE);    // [512][512]
constexpr size_t SZ_H    = 512ull * 512 * 4;
constexpr size_t O_H1    = ALN(O_H0 + SZ_H);
constexpr size_t O_AM    = ALN(O_H1 + SZ_H);        // [512][100]
constexpr size_t O_BT    = ALN(O_AM + SZ_WTAB);     // [100][512]

// ---------------- kernels ----------------

// sentinel-fill the h-exchange slots (4*512*128 = 262144 words)
__global__ void k_init_ex(uint32_t* __restrict__ ex) {
  ex[(size_t)blockIdx.x * 256 + threadIdx.x] = SENT;
}

// embeds: x0[i][0:100] = word_emb[wi[i]], x0[i][100:125] = pos_emb[pi[i]]
__global__ void k_embed(const int* __restrict__ wi, const int* __restrict__ pi,
                        const float* __restrict__ we, const float* __restrict__ pe,
                        float* __restrict__ x0) {
  int i = blockIdx.x, k = threadIdx.x;
  if (k < 100)      x0[i * 125 + k] = we[(size_t)wi[i] * 100 + k];
  else if (k < 125) x0[i * 125 + k] = pe[(size_t)pi[i] * 25 + (k - 100)];
}

// dst[k][m] = src[m][colOff+k] for k<colCnt else 0 ; dst dims [dstRows][srcRows]
__global__ void k_transpose(const float* __restrict__ src, int srcRows, int srcCols,
                            int colOff, int colCnt, int dstRows, float* __restrict__ dst) {
  __shared__ float tile[32][33];
  int k0 = blockIdx.x * 32, m0 = blockIdx.y * 32;
  int tx = threadIdx.x, ty = threadIdx.y;
#pragma unroll
  for (int i = 0; i < 4; i++) {
    int m = m0 + ty + i * 8, k = k0 + tx;
    float v = 0.f;
    if (m < srcRows && k < colCnt) v = src[(size_t)m * srcCols + colOff + k];
    tile[ty + i * 8][tx] = v;
  }
  __syncthreads();
#pragma unroll
  for (int i = 0; i < 4; i++) {
    int k = k0 + ty + i * 8, m = m0 + tx;
    if (k < dstRows && m < srcRows) dst[(size_t)k * srcRows + m] = tile[tx][ty + i * 8];
  }
}

// Whh (4 x [1024][256] f32) -> packed f16 pairs, layout [ld][chunk(32)][owner(1024)]
// as uint4 so the LSTM prologue does 32 coalesced dwordx4 loads per thread.
// u32 index inside ld: (kp>>2)*4096 + owner*4 + (kp&3), kp = 0..127 pair idx.
__global__ void k_packwhh(const float* __restrict__ whh0, const float* __restrict__ whh1,
                          uint32_t* __restrict__ wpk) {
  int ld = blockIdx.x;   // layer*2 + dir
  int kp = blockIdx.y;   // 0..127
  int o  = threadIdx.x;  // 0..1023 owner = b*512 + t
  const float* W = (ld < 2) ? (whh0 + (size_t)ld * 1024 * 256)
                            : (whh1 + (size_t)(ld - 2) * 1024 * 256);
  int b = o >> 9, t = o & 511;
  int gate = t >> 7, u = t & 127;
  int R = gate * 256 + b * 128 + u;
  f16x2 p;
  p.x = (_Float16)W[(size_t)R * 256 + 2 * kp];
  p.y = (_Float16)W[(size_t)R * 256 + 2 * kp + 1];
  wpk[(size_t)ld * 131072 + (size_t)(kp >> 2) * 4096 + (size_t)o * 4 + (kp & 3)] =
      __builtin_bit_cast(uint32_t, p);
}

// out[gr][col] (or transposed) = sum_k X[xr][k] * WT[k][col] + bias1[col]+bias2[col]
// WT is [Kpad][Nn] with rows >= Kreal zero-filled.
__global__ __launch_bounds__(256) void k_gemm(
    const float* __restrict__ X, const float* __restrict__ WT,
    const float* __restrict__ bias1, const float* __restrict__ bias2,
    float* __restrict__ out, int Mm, int Nn, int Kpad, int Kreal, int ldx,
    int flipX, int outT) {
  __shared__ float XS[32][64];
  int tid = threadIdx.x;
  int cl = tid & 63, rg = tid >> 6;
  int col = blockIdx.y * 64 + cl;
  int colr = (col < Nn) ? col : (Nn - 1);
  int row0 = blockIdx.x * 32;
  float acc[8];
#pragma unroll
  for (int r = 0; r < 8; r++) acc[r] = 0.f;
  for (int k0 = 0; k0 < Kpad; k0 += 64) {
#pragma unroll
    for (int ii = 0; ii < 8; ii++) {
      int idx = ii * 256 + tid;
      int r = idx >> 6, kk = idx & 63;
      int gr = row0 + r;
      int xr = flipX ? (Mm - 1 - gr) : gr;
      int k = k0 + kk;
      XS[r][kk] = (k < Kreal) ? X[(size_t)xr * ldx + k] : 0.f;
    }
    __syncthreads();
#pragma unroll 4
    for (int kk = 0; kk < 64; kk++) {
      float w = WT[(size_t)(k0 + kk) * Nn + colr];
#pragma unroll
      for (int r = 0; r < 8; r++) acc[r] += XS[rg * 8 + r][kk] * w;
    }
    __syncthreads();
  }
  if (col < Nn) {
    float bb = (bias1 ? bias1[col] : 0.f) + (bias2 ? bias2[col] : 0.f);
#pragma unroll
    for (int r = 0; r < 8; r++) {
      int gr = row0 + rg * 8 + r;
      float v = acc[r] + bb;
      if (outT) out[(size_t)col * Mm + gr] = v;
      else      out[(size_t)gr * Nn + col] = v;
    }
  }
}

// Recurrent scan. Grid = 4 blocks: (dir = bx>>1, half = bx&1). 512 threads.
// Thread t owns Whh row R = (t>>7)*256 + b*128 + (t&127) in 32 NAMED uint4
// registers. Per step: all threads dot; wave0 (t<64) computes 2 hidden units
// each (gates+publish); wave1 (t in 64..127) polls partner half.
__global__ __launch_bounds__(512, 2) void k_lstm(
    const float* __restrict__ preBase, const uint32_t* __restrict__ wpkL,
    float* __restrict__ hout, uint32_t* __restrict__ exL) {
  int d = blockIdx.x >> 1, b = blockIdx.x & 1;
  int t = threadIdx.x;
  const float* pre = preBase + (size_t)d * 512 * 1024;
  const uint32_t* wsrc = wpkL + (size_t)d * 131072;
  uint32_t* ex = exL + (size_t)d * 512 * 128;

  __shared__ __align__(16) uint32_t h2[128];  // packed f16 pairs of full h[256]
  __shared__ __align__(8) float gl[512];      // gate pre-activations

  // ---- weight prologue: 32 named uint4 = 128 pinned VGPRs ----
  const uint4* wv = (const uint4*)wsrc;
  const int o = b * 512 + t;
#define WLOAD(i) uint4 W##i = wv[(i) * 1024 + o];
  WLOAD(0)  WLOAD(1)  WLOAD(2)  WLOAD(3)  WLOAD(4)  WLOAD(5)  WLOAD(6)  WLOAD(7)
  WLOAD(8)  WLOAD(9)  WLOAD(10) WLOAD(11) WLOAD(12) WLOAD(13) WLOAD(14) WLOAD(15)
  WLOAD(16) WLOAD(17) WLOAD(18) WLOAD(19) WLOAD(20) WLOAD(21) WLOAD(22) WLOAD(23)
  WLOAD(24) WLOAD(25) WLOAD(26) WLOAD(27) WLOAD(28) WLOAD(29) WLOAD(30) WLOAD(31)
#undef WLOAD
  // Pin each component as an asm-defined SSA value: not rematerializable,
  // must live in VGPRs across the step loop.
#define WPIN(i) asm volatile("" : "+v"(W##i.x), "+v"(W##i.y), "+v"(W##i.z), "+v"(W##i.w));
  WPIN(0)  WPIN(1)  WPIN(2)  WPIN(3)  WPIN(4)  WPIN(5)  WPIN(6)  WPIN(7)
  WPIN(8)  WPIN(9)  WPIN(10) WPIN(11) WPIN(12) WPIN(13) WPIN(14) WPIN(15)
  WPIN(16) WPIN(17) WPIN(18) WPIN(19) WPIN(20) WPIN(21) WPIN(22) WPIN(23)
  WPIN(24) WPIN(25) WPIN(26) WPIN(27) WPIN(28) WPIN(29) WPIN(30) WPIN(31)
#undef WPIN

  if (t < 128) h2[t] = 0u;
  float c0 = 0.f, c1 = 0.f;  // wave0: cell state for units 2t, 2t+1
  const int gate = t >> 7, u = t & 127;
  const int RR = gate * 256 + b * 128 + u;
  __syncthreads();

  float pcur = pre[RR];
  for (int s = 0; s < 512; s++) {
    float pnext = (s < 511) ? pre[(size_t)(s + 1) * 1024 + RR] : 0.f;
    // 128-pair dot against named weight registers, 4 accumulator chains
    float a0 = pcur, a1 = 0.f, a2 = 0.f, a3 = 0.f;
    const uint4* h4 = (const uint4*)h2;
#define DOT(i) { uint4 hv = h4[i];                 \
      a0 = fdot2f(W##i.x, hv.x, a0);               \
      a1 = fdot2f(W##i.y, hv.y, a1);               \
      a2 = fdot2f(W##i.z, hv.z, a2);               \
      a3 = fdot2f(W##i.w, hv.w, a3); }
    DOT(0)  DOT(1)  DOT(2)  DOT(3)  DOT(4)  DOT(5)  DOT(6)  DOT(7)
    DOT(8)  DOT(9)  DOT(10) DOT(11) DOT(12) DOT(13) DOT(14) DOT(15)
    DOT(16) DOT(17) DOT(18) DOT(19) DOT(20) DOT(21) DOT(22) DOT(23)
    DOT(24) DOT(25) DOT(26) DOT(27) DOT(28) DOT(29) DOT(30) DOT(31)
#undef DOT
    gl[t] = (a0 + a1) + (a2 + a3);
    __syncthreads();
    if (t < 64) {
      // gates for units (2t, 2t+1); gl layout: [i(128) f(128) g(128) o(128)]
      const float2* GL2 = (const float2*)gl;
      float2 gi = GL2[t];
      float2 gf = GL2[64 + t];
      float2 gg = GL2[128 + t];
      float2 go = GL2[192 + t];
      c0 = fsigm(gf.x) * c0 + fsigm(gi.x) * ftanh(gg.x);
      c1 = fsigm(gf.y) * c1 + fsigm(gi.y) * ftanh(gg.y);
      float hA = fsigm(go.x) * ftanh(c0);
      float hB = fsigm(go.y) * ftanh(c1);
      f16x2 p;
      p.x = (_Float16)hA;
      p.y = (_Float16)hB;
      uint32_t pk = __builtin_bit_cast(uint32_t, p);
      // publish to partner FIRST (critical path), then local stores
      __hip_atomic_store(&ex[(size_t)s * 128 + b * 64 + t], pk,
                         __ATOMIC_RELAXED, SCOPE_AGENT);
      h2[b * 64 + t] = pk;
      int pos = (d == 0) ? s : (511 - s);
      *(float2*)&hout[(size_t)pos * 512 + d * 256 + b * 128 + 2 * t] =
          make_float2(hA, hB);
    } else if (t < 128) {
      // wave1: poll partner half (overlaps wave0's transcendentals)
      int tt = t - 64;
      uint32_t q;
      do {
        q = __hip_atomic_load(&ex[(size_t)s * 128 + (b ^ 1) * 64 + tt],
                              __ATOMIC_RELAXED, SCOPE_AGENT);
      } while (__any(q == SENT));
      h2[(b ^ 1) * 64 + tt] = q;
    }
    pcur = pnext;
    __syncthreads();
  }
}

// scores[i][j] = b2 + sum_m W2[m] * tanh(a[i][m] + bT[m][j])   (b1 folded into a)
__global__ __launch_bounds__(512) void k_score(
    const float* __restrict__ am, const float* __restrict__ bT,
    const float* __restrict__ W2, const float* __restrict__ b2,
    float* __restrict__ out) {
  int i = blockIdx.x;
  int j = threadIdx.x;
  __shared__ float aL[100], w2L[100];
  if (j < 100) { aL[j] = am[(size_t)i * 100 + j]; w2L[j] = W2[j]; }
  __syncthreads();
  float acc = b2[0];
#pragma unroll 4
  for (int m = 0; m < 100; m++)
    acc += w2L[m] * ftanh(aL[m] + bT[(size_t)m * 512 + j]);
  out[(size_t)i * 512 + j] = acc;
}

// ---------------- launch ----------------
extern "C" void kernel_launch(void* const* d_in, const int* in_sizes, int n_in,
                              void* d_out, int out_size, void* d_ws, size_t ws_size,
                              hipStream_t stream) {
  const int*   wi   = (const int*)d_in[0];
  const int*   pi   = (const int*)d_in[1];
  const float* we   = (const float*)d_in[2];
  const float* pe   = (const float*)d_in[3];
  const float* Wih0 = (const float*)d_in[4];
  const float* Whh0 = (const float*)d_in[5];
  const float* bih0 = (const float*)d_in[6];
  const float* bhh0 = (const float*)d_in[7];
  const float* Wih1 = (const float*)d_in[8];
  const float* Whh1 = (const float*)d_in[9];
  const float* bih1 = (const float*)d_in[10];
  const float* bhh1 = (const float*)d_in[11];
  const float* W1   = (const float*)d_in[12];
  const float* b1   = (const float*)d_in[13];
  const float* W2   = (const float*)d_in[14];
  const float* b2   = (const float*)d_in[15];

  char* ws = (char*)d_ws;
  uint32_t* ex    = (uint32_t*)(ws + O_EX);
  uint32_t* wpk   = (uint32_t*)(ws + O_WPK);
  float* x0    = (float*)(ws + O_X0);
  float* wtih0 = (float*)(ws + O_WTIH0);
  float* wtih1 = (float*)(ws + O_WTIH1);
  float* wta   = (float*)(ws + O_WTA);
  float* wtb   = (float*)(ws + O_WTB);
  float* pre0  = (float*)(ws + O_PRE0);
  float* pre1  = (float*)(ws + O_PRE1);
  float* h0    = (float*)(ws + O_H0);
  float* h1    = (float*)(ws + O_H1);
  float* am    = (float*)(ws + O_AM);
  float* bt    = (float*)(ws + O_BT);
  float* out   = (float*)d_out;

  k_init_ex<<<1024, 256, 0, stream>>>(ex);  // 262144 words

  k_embed<<<512, 128, 0, stream>>>(wi, pi, we, pe, x0);

  dim3 tb(32, 8);
  k_transpose<<<dim3(4, 32),  tb, 0, stream>>>(Wih0,              1024, 125, 0,   125, 128, wtih0);
  k_transpose<<<dim3(4, 32),  tb, 0, stream>>>(Wih0 + 1024 * 125, 1024, 125, 0,   125, 128, wtih0 + 128 * 1024);
  k_transpose<<<dim3(16, 32), tb, 0, stream>>>(Wih1,              1024, 512, 0,   512, 512, wtih1);
  k_transpose<<<dim3(16, 32), tb, 0, stream>>>(Wih1 + 1024 * 512, 1024, 512, 0,   512, 512, wtih1 + 512 * 1024);
  k_transpose<<<dim3(16, 4),  tb, 0, stream>>>(W1,                100, 1024, 0,   512, 512, wta);
  k_transpose<<<dim3(16, 4),  tb, 0, stream>>>(W1,                100, 1024, 512, 512, 512, wtb);

  k_packwhh<<<dim3(4, 128), 1024, 0, stream>>>(Whh0, Whh1, wpk);

  for (int d = 0; d < 2; d++)
    k_gemm<<<dim3(16, 16), 256, 0, stream>>>(x0, wtih0 + (size_t)d * 128 * 1024,
        bih0 + d * 1024, bhh0 + d * 1024, pre0 + (size_t)d * 512 * 1024,
        512, 1024, 128, 125, 125, d, 0);

  k_lstm<<<4, 512, 0, stream>>>(pre0, wpk, h0, ex);

  for (int d = 0; d < 2; d++)
    k_gemm<<<dim3(16, 16), 256, 0, stream>>>(h0, wtih1 + (size_t)d * 512 * 1024,
        bih1 + d * 1024, bhh1 + d * 1024, pre1 + (size_t)d * 512 * 1024,
        512, 1024, 512, 512, 512, d, 0);

  k_lstm<<<4, 512, 0, stream>>>(pre1, wpk + 2 * 131072, h1, ex + 2ull * 512 * 128);

  k_gemm<<<dim3(16, 2), 256, 0, stream>>>(h1, wta, b1, nullptr, am, 512, 100, 512, 512, 512, 0, 0);
  k_gemm<<<dim3(16, 2), 256, 0, stream>>>(h1, wtb, nullptr, nullptr, bt, 512, 100, 512, 512, 512, 0, 1);

  k_score<<<512, 512, 0, stream>>>(am, bt, W2, b2, out);
}

// Round 6
// 2445.663 us; speedup vs baseline: 1.1181x; 1.1181x over previous
//
#include <hip/hip_runtime.h>
#include <hip/hip_bf16.h>
#include <stdint.h>

// ---------------------------------------------------------------------------
// Kiperwasser parser: embed -> BiLSTM(2 layers, H=256, N=512) -> pair scorer.
// Recurrent scan: 4 blocks (2 per direction) x 1024 threads. Each thread owns
// HALF a Whh row (64 f16 pairs = 16 named uint4 = 64 VGPRs) so total demand
// (~100 VGPR) fits the 128-VGPR cap a 1024-thread block forces -- rounds 2-4
// proved that a 128-VGPR weight footprint gets spilled to scratch (VGPR_Count
// stuck at 80-84, ~1.9us/step of L2/scratch reload). Partial dots combine via
// LDS; h halves exchange between partner blocks through sentinel-initialized
// global slots (relaxed agent atomics, one write per word per launch).
// ---------------------------------------------------------------------------

typedef _Float16 f16x2 __attribute__((ext_vector_type(2)));

#define SCOPE_AGENT __HIP_MEMORY_SCOPE_AGENT
constexpr uint32_t SENT = 0x7FFF7FFFu;  // f16 NaN pair: unreachable as packed h

__device__ __forceinline__ float fdot2f(uint32_t w, uint32_t h, float acc) {
#if __has_builtin(__builtin_amdgcn_fdot2)
  return __builtin_amdgcn_fdot2(__builtin_bit_cast(f16x2, w),
                                __builtin_bit_cast(f16x2, h), acc, false);
#else
  f16x2 a = __builtin_bit_cast(f16x2, w);
  f16x2 b = __builtin_bit_cast(f16x2, h);
  return acc + (float)a.x * (float)b.x + (float)a.y * (float)b.y;
#endif
}

__device__ __forceinline__ uint32_t packpair(float x, float y) {
  f16x2 p;
  p.x = (_Float16)x;
  p.y = (_Float16)y;
  return __builtin_bit_cast(uint32_t, p);
}

__device__ __forceinline__ float fsigm(float x) { return 1.f / (1.f + __expf(-x)); }
__device__ __forceinline__ float ftanh(float x) {
  float e = __expf(2.f * x);
  return 1.f - 2.f / (e + 1.f);
}

// ---------------- workspace layout (bytes) ----------------
constexpr size_t ALN(size_t x) { return (x + 1023) & ~(size_t)1023; }
constexpr size_t O_EX    = 0;                       // 4(ld) * 512 * 128 u32 = 1 MB
constexpr size_t SZ_EX   = 4ull * 512 * 128 * 4;
constexpr size_t O_WPK   = ALN(O_EX + SZ_EX);       // 4(ld) * 16chunk * 2048owner * uint4 = 2 MB
constexpr size_t SZ_WPK  = 4ull * 16 * 2048 * 16;
constexpr size_t O_X0    = ALN(O_WPK + SZ_WPK);     // 512 x 125 f32
constexpr size_t SZ_X0   = 512ull * 125 * 4;
constexpr size_t O_WTIH0 = ALN(O_X0 + SZ_X0);       // 2 x [128][1024]
constexpr size_t SZ_WTIH0 = 2ull * 128 * 1024 * 4;
constexpr size_t O_WTIH1 = ALN(O_WTIH0 + SZ_WTIH0); // 2 x [512][1024]
constexpr size_t SZ_WTIH1 = 2ull * 512 * 1024 * 4;
constexpr size_t O_WTA   = ALN(O_WTIH1 + SZ_WTIH1); // [512][100]
constexpr size_t SZ_WTAB = 512ull * 100 * 4;
constexpr size_t O_WTB   = ALN(O_WTA + SZ_WTAB);    // [512][100]
constexpr size_t O_PRE0  = ALN(O_WTB + SZ_WTAB);    // 2 x [512][1024]
constexpr size_t SZ_PRE  = 2ull * 512 * 1024 * 4;
constexpr size_t O_PRE1  = ALN(O_PRE0 + SZ_PRE);
constexpr size_t O_H0    = ALN(O_PRE1 + SZ_PRE);    // [512][512]
constexpr size_t SZ_H    = 512ull * 512 * 4;
constexpr size_t O_H1    = ALN(O_H0 + SZ_H);
constexpr size_t O_AM    = ALN(O_H1 + SZ_H);        // [512][100]
constexpr size_t O_BT    = ALN(O_AM + SZ_WTAB);     // [100][512]

// ---------------- kernels ----------------

// sentinel-fill the h-exchange slots (4*512*128 = 262144 words)
__global__ void k_init_ex(uint32_t* __restrict__ ex) {
  ex[(size_t)blockIdx.x * 256 + threadIdx.x] = SENT;
}

// embeds: x0[i][0:100] = word_emb[wi[i]], x0[i][100:125] = pos_emb[pi[i]]
__global__ void k_embed(const int* __restrict__ wi, const int* __restrict__ pi,
                        const float* __restrict__ we, const float* __restrict__ pe,
                        float* __restrict__ x0) {
  int i = blockIdx.x, k = threadIdx.x;
  if (k < 100)      x0[i * 125 + k] = we[(size_t)wi[i] * 100 + k];
  else if (k < 125) x0[i * 125 + k] = pe[(size_t)pi[i] * 25 + (k - 100)];
}

// dst[k][m] = src[m][colOff+k] for k<colCnt else 0 ; dst dims [dstRows][srcRows]
__global__ void k_transpose(const float* __restrict__ src, int srcRows, int srcCols,
                            int colOff, int colCnt, int dstRows, float* __restrict__ dst) {
  __shared__ float tile[32][33];
  int k0 = blockIdx.x * 32, m0 = blockIdx.y * 32;
  int tx = threadIdx.x, ty = threadIdx.y;
#pragma unroll
  for (int i = 0; i < 4; i++) {
    int m = m0 + ty + i * 8, k = k0 + tx;
    float v = 0.f;
    if (m < srcRows && k < colCnt) v = src[(size_t)m * srcCols + colOff + k];
    tile[ty + i * 8][tx] = v;
  }
  __syncthreads();
#pragma unroll
  for (int i = 0; i < 4; i++) {
    int k = k0 + ty + i * 8, m = m0 + tx;
    if (k < dstRows && m < srcRows) dst[(size_t)k * srcRows + m] = tile[tx][ty + i * 8];
  }
}

// Whh (4 x [1024][256] f32) -> packed f16 pairs, layout [ld][chunk(16)][owner(2048)]
// uint4. Owner o = b*1024 + t; thread t<512 covers k-half = b (own), t>=512
// covers k-half = b^1 (partner). Chunk c covers k = khalf*128 + c*8 .. +7.
__global__ void k_packwhh(const float* __restrict__ whh0, const float* __restrict__ whh1,
                          uint32_t* __restrict__ wpk) {
  int ld = blockIdx.x;                        // layer*2 + dir
  int c  = blockIdx.y;                        // 0..15
  int o  = blockIdx.z * 1024 + threadIdx.x;   // 0..2047
  const float* W = (ld < 2) ? (whh0 + (size_t)ld * 1024 * 256)
                            : (whh1 + (size_t)(ld - 2) * 1024 * 256);
  int b = o >> 10, t = o & 1023;
  int hi = t >> 9, tr = t & 511;
  int gate = tr >> 7, u = tr & 127;
  int R = gate * 256 + b * 128 + u;
  int khalf = hi ? (b ^ 1) : b;
  const float* src = W + (size_t)R * 256 + khalf * 128 + c * 8;
  uint4 outv;
  outv.x = packpair(src[0], src[1]);
  outv.y = packpair(src[2], src[3]);
  outv.z = packpair(src[4], src[5]);
  outv.w = packpair(src[6], src[7]);
  ((uint4*)wpk)[(size_t)ld * 32768 + (size_t)c * 2048 + o] = outv;
}

// out[gr][col] (or transposed) = sum_k X[xr][k] * WT[k][col] + bias1[col]+bias2[col]
// WT is [Kpad][Nn] with rows >= Kreal zero-filled.
__global__ __launch_bounds__(256) void k_gemm(
    const float* __restrict__ X, const float* __restrict__ WT,
    const float* __restrict__ bias1, const float* __restrict__ bias2,
    float* __restrict__ out, int Mm, int Nn, int Kpad, int Kreal, int ldx,
    int flipX, int outT) {
  __shared__ float XS[32][64];
  int tid = threadIdx.x;
  int cl = tid & 63, rg = tid >> 6;
  int col = blockIdx.y * 64 + cl;
  int colr = (col < Nn) ? col : (Nn - 1);
  int row0 = blockIdx.x * 32;
  float acc[8];
#pragma unroll
  for (int r = 0; r < 8; r++) acc[r] = 0.f;
  for (int k0 = 0; k0 < Kpad; k0 += 64) {
#pragma unroll
    for (int ii = 0; ii < 8; ii++) {
      int idx = ii * 256 + tid;
      int r = idx >> 6, kk = idx & 63;
      int gr = row0 + r;
      int xr = flipX ? (Mm - 1 - gr) : gr;
      int k = k0 + kk;
      XS[r][kk] = (k < Kreal) ? X[(size_t)xr * ldx + k] : 0.f;
    }
    __syncthreads();
#pragma unroll 4
    for (int kk = 0; kk < 64; kk++) {
      float w = WT[(size_t)(k0 + kk) * Nn + colr];
#pragma unroll
      for (int r = 0; r < 8; r++) acc[r] += XS[rg * 8 + r][kk] * w;
    }
    __syncthreads();
  }
  if (col < Nn) {
    float bb = (bias1 ? bias1[col] : 0.f) + (bias2 ? bias2[col] : 0.f);
#pragma unroll
    for (int r = 0; r < 8; r++) {
      int gr = row0 + rg * 8 + r;
      float v = acc[r] + bb;
      if (outT) out[(size_t)col * Mm + gr] = v;
      else      out[(size_t)gr * Nn + col] = v;
    }
  }
}

// Recurrent scan. Grid = 4 blocks: (dir = bx>>1, half = bx&1). 1024 threads.
// Thread t: row-part tr = t&511 (gate-row R = (tr>>7)*256 + b*128 + (tr&127)),
// k-half = (t<512 ? own : partner). 16 named uint4 = 64 weight VGPRs/thread.
__global__ __launch_bounds__(1024) void k_lstm(
    const float* __restrict__ preBase, const uint32_t* __restrict__ wpkL,
    float* __restrict__ hout, uint32_t* __restrict__ exL) {
  int d = blockIdx.x >> 1, b = blockIdx.x & 1;
  int t = threadIdx.x;
  int tr = t & 511, hi = t >> 9;
  const float* pre = preBase + (size_t)d * 512 * 1024;
  uint32_t* ex = exL + (size_t)d * 512 * 128;
  const uint4* wv = (const uint4*)(wpkL + (size_t)d * 131072);

  __shared__ __align__(16) uint32_t h2[128];  // packed f16 pairs of full h[256]
  __shared__ __align__(8) float shp[1024];    // partial dots (own: +pre)

  const int o = b * 1024 + t;
  const int khalf = hi ? (b ^ 1) : b;

  // ---- weight prologue: 16 named uint4 = 64 pinned VGPRs ----
#define WLOAD(i) uint4 W##i = wv[(i) * 2048 + o];
  WLOAD(0)  WLOAD(1)  WLOAD(2)  WLOAD(3)  WLOAD(4)  WLOAD(5)  WLOAD(6)  WLOAD(7)
  WLOAD(8)  WLOAD(9)  WLOAD(10) WLOAD(11) WLOAD(12) WLOAD(13) WLOAD(14) WLOAD(15)
#undef WLOAD
#define WPIN(i) asm volatile("" : "+v"(W##i.x), "+v"(W##i.y), "+v"(W##i.z), "+v"(W##i.w));
  WPIN(0)  WPIN(1)  WPIN(2)  WPIN(3)  WPIN(4)  WPIN(5)  WPIN(6)  WPIN(7)
  WPIN(8)  WPIN(9)  WPIN(10) WPIN(11) WPIN(12) WPIN(13) WPIN(14) WPIN(15)
#undef WPIN

  if (t < 128) h2[t] = 0u;
  float c0 = 0.f, c1 = 0.f;  // wave0: cell state for units 2t, 2t+1
  const int gate = tr >> 7, u = tr & 127;
  const int RR = gate * 256 + b * 128 + u;
  float pcur = (t < 512) ? pre[RR] : 0.f;
  __syncthreads();

  for (int s = 0; s < 512; s++) {
    float pnext = (t < 512 && s < 511) ? pre[(size_t)(s + 1) * 1024 + RR] : 0.f;
    // 64-pair half-row dot; a0 seeded with pre (0 for partner-half threads)
    float a0 = pcur, a1 = 0.f, a2 = 0.f, a3 = 0.f;
    const uint4* hb = ((const uint4*)h2) + khalf * 16;
#define DOT(i) { uint4 hv = hb[i];                 \
      a0 = fdot2f(W##i.x, hv.x, a0);               \
      a1 = fdot2f(W##i.y, hv.y, a1);               \
      a2 = fdot2f(W##i.z, hv.z, a2);               \
      a3 = fdot2f(W##i.w, hv.w, a3); }
    DOT(0)  DOT(1)  DOT(2)  DOT(3)  DOT(4)  DOT(5)  DOT(6)  DOT(7)
    DOT(8)  DOT(9)  DOT(10) DOT(11) DOT(12) DOT(13) DOT(14) DOT(15)
#undef DOT
    shp[t] = (a0 + a1) + (a2 + a3);
    __syncthreads();
    if (t < 64) {
      // units (2t, 2t+1): sum own+partner halves; shp float2 view:
      // gate g units (2t,2t+1) -> SP2[g*64+t] (own) + SP2[256+g*64+t] (partner)
      const float2* SP2 = (const float2*)shp;
      float2 giA = SP2[t],       giB = SP2[256 + t];
      float2 gfA = SP2[64 + t],  gfB = SP2[320 + t];
      float2 ggA = SP2[128 + t], ggB = SP2[384 + t];
      float2 goA = SP2[192 + t], goB = SP2[448 + t];
      float gi0 = giA.x + giB.x, gi1 = giA.y + giB.y;
      float gf0 = gfA.x + gfB.x, gf1 = gfA.y + gfB.y;
      float gg0 = ggA.x + ggB.x, gg1 = ggA.y + ggB.y;
      float go0 = goA.x + goB.x, go1 = goA.y + goB.y;
      c0 = fsigm(gf0) * c0 + fsigm(gi0) * ftanh(gg0);
      c1 = fsigm(gf1) * c1 + fsigm(gi1) * ftanh(gg1);
      float hA = fsigm(go0) * ftanh(c0);
      float hB = fsigm(go1) * ftanh(c1);
      uint32_t pk = packpair(hA, hB);
      // publish to partner FIRST (critical path), then local stores
      __hip_atomic_store(&ex[(size_t)s * 128 + b * 64 + t], pk,
                         __ATOMIC_RELAXED, SCOPE_AGENT);
      h2[b * 64 + t] = pk;
      int pos = (d == 0) ? s : (511 - s);
      *(float2*)&hout[(size_t)pos * 512 + d * 256 + b * 128 + 2 * t] =
          make_float2(hA, hB);
    } else if (t < 128) {
      // wave1: poll partner half (overlaps wave0's transcendentals)
      int tt = t - 64;
      uint32_t q;
      do {
        q = __hip_atomic_load(&ex[(size_t)s * 128 + (b ^ 1) * 64 + tt],
                              __ATOMIC_RELAXED, SCOPE_AGENT);
      } while (__any(q == SENT));
      h2[(b ^ 1) * 64 + tt] = q;
    }
    pcur = pnext;
    __syncthreads();
  }
}

// scores[i][j] = b2 + sum_m W2[m] * tanh(a[i][m] + bT[m][j])   (b1 folded into a)
__global__ __launch_bounds__(512) void k_score(
    const float* __restrict__ am, const float* __restrict__ bT,
    const float* __restrict__ W2, const float* __restrict__ b2,
    float* __restrict__ out) {
  int i = blockIdx.x;
  int j = threadIdx.x;
  __shared__ float aL[100], w2L[100];
  if (j < 100) { aL[j] = am[(size_t)i * 100 + j]; w2L[j] = W2[j]; }
  __syncthreads();
  float acc = b2[0];
#pragma unroll 4
  for (int m = 0; m < 100; m++)
    acc += w2L[m] * ftanh(aL[m] + bT[(size_t)m * 512 + j]);
  out[(size_t)i * 512 + j] = acc;
}

// ---------------- launch ----------------
extern "C" void kernel_launch(void* const* d_in, const int* in_sizes, int n_in,
                              void* d_out, int out_size, void* d_ws, size_t ws_size,
                              hipStream_t stream) {
  const int*   wi   = (const int*)d_in[0];
  const int*   pi   = (const int*)d_in[1];
  const float* we   = (const float*)d_in[2];
  const float* pe   = (const float*)d_in[3];
  const float* Wih0 = (const float*)d_in[4];
  const float* Whh0 = (const float*)d_in[5];
  const float* bih0 = (const float*)d_in[6];
  const float* bhh0 = (const float*)d_in[7];
  const float* Wih1 = (const float*)d_in[8];
  const float* Whh1 = (const float*)d_in[9];
  const float* bih1 = (const float*)d_in[10];
  const float* bhh1 = (const float*)d_in[11];
  const float* W1   = (const float*)d_in[12];
  const float* b1   = (const float*)d_in[13];
  const float* W2   = (const float*)d_in[14];
  const float* b2   = (const float*)d_in[15];

  char* ws = (char*)d_ws;
  uint32_t* ex    = (uint32_t*)(ws + O_EX);
  uint32_t* wpk   = (uint32_t*)(ws + O_WPK);
  float* x0    = (float*)(ws + O_X0);
  float* wtih0 = (float*)(ws + O_WTIH0);
  float* wtih1 = (float*)(ws + O_WTIH1);
  float* wta   = (float*)(ws + O_WTA);
  float* wtb   = (float*)(ws + O_WTB);
  float* pre0  = (float*)(ws + O_PRE0);
  float* pre1  = (float*)(ws + O_PRE1);
  float* h0    = (float*)(ws + O_H0);
  float* h1    = (float*)(ws + O_H1);
  float* am    = (float*)(ws + O_AM);
  float* bt    = (float*)(ws + O_BT);
  float* out   = (float*)d_out;

  k_init_ex<<<1024, 256, 0, stream>>>(ex);  // 262144 words

  k_embed<<<512, 128, 0, stream>>>(wi, pi, we, pe, x0);

  dim3 tb(32, 8);
  k_transpose<<<dim3(4, 32),  tb, 0, stream>>>(Wih0,              1024, 125, 0,   125, 128, wtih0);
  k_transpose<<<dim3(4, 32),  tb, 0, stream>>>(Wih0 + 1024 * 125, 1024, 125, 0,   125, 128, wtih0 + 128 * 1024);
  k_transpose<<<dim3(16, 32), tb, 0, stream>>>(Wih1,              1024, 512, 0,   512, 512, wtih1);
  k_transpose<<<dim3(16, 32), tb, 0, stream>>>(Wih1 + 1024 * 512, 1024, 512, 0,   512, 512, wtih1 + 512 * 1024);
  k_transpose<<<dim3(16, 4),  tb, 0, stream>>>(W1,                100, 1024, 0,   512, 512, wta);
  k_transpose<<<dim3(16, 4),  tb, 0, stream>>>(W1,                100, 1024, 512, 512, 512, wtb);

  k_packwhh<<<dim3(4, 16, 2), 1024, 0, stream>>>(Whh0, Whh1, wpk);

  for (int d = 0; d < 2; d++)
    k_gemm<<<dim3(16, 16), 256, 0, stream>>>(x0, wtih0 + (size_t)d * 128 * 1024,
        bih0 + d * 1024, bhh0 + d * 1024, pre0 + (size_t)d * 512 * 1024,
        512, 1024, 128, 125, 125, d, 0);

  k_lstm<<<4, 1024, 0, stream>>>(pre0, wpk, h0, ex);

  for (int d = 0; d < 2; d++)
    k_gemm<<<dim3(16, 16), 256, 0, stream>>>(h0, wtih1 + (size_t)d * 512 * 1024,
        bih1 + d * 1024, bhh1 + d * 1024, pre1 + (size_t)d * 512 * 1024,
        512, 1024, 512, 512, 512, d, 0);

  k_lstm<<<4, 1024, 0, stream>>>(pre1, wpk + 2 * 131072, h1, ex + 2ull * 512 * 128);

  k_gemm<<<dim3(16, 2), 256, 0, stream>>>(h1, wta, b1, nullptr, am, 512, 100, 512, 512, 512, 0, 0);
  k_gemm<<<dim3(16, 2), 256, 0, stream>>>(h1, wtb, nullptr, nullptr, bt, 512, 100, 512, 512, 512, 0, 1);

  k_score<<<512, 512, 0, stream>>>(am, bt, W2, b2, out);
}

// Round 7
// 2445.466 us; speedup vs baseline: 1.1182x; 1.0001x over previous
//
#include <hip/hip_runtime.h>
#include <hip/hip_bf16.h>
#include <stdint.h>

// ---------------------------------------------------------------------------
// Kiperwasser parser: embed -> BiLSTM(2 layers, H=256, N=512) -> pair scorer.
// Recurrent scan: 4 blocks (2 per direction) x 1024 threads; each thread owns
// HALF a Whh row (64 f16 pairs = 16 named uint4 = 64 VGPRs).
// KEY FIX (round 7): amdgpu_waves_per_eu(4,4) pins the occupancy target to
// exactly the 4 waves/EU a 1024-thread workgroup needs. Rounds 2-6 showed the
// backend targets ~8 waves/EU (64-VGPR budget) and spills the weights to
// scratch (VGPR_Count 52-84), making every step stream 256 KB/block from L2 =
// per-CU L2 BW wall (~1.6us/step). With min=max=4 the budget is 128 VGPRs and
// the ~94-VGPR demand fits with no spill.
// ---------------------------------------------------------------------------

typedef _Float16 f16x2 __attribute__((ext_vector_type(2)));

#define SCOPE_AGENT __HIP_MEMORY_SCOPE_AGENT
constexpr uint32_t SENT = 0x7FFF7FFFu;  // f16 NaN pair: unreachable as packed h

__device__ __forceinline__ float fdot2f(uint32_t w, uint32_t h, float acc) {
#if __has_builtin(__builtin_amdgcn_fdot2)
  return __builtin_amdgcn_fdot2(__builtin_bit_cast(f16x2, w),
                                __builtin_bit_cast(f16x2, h), acc, false);
#else
  f16x2 a = __builtin_bit_cast(f16x2, w);
  f16x2 b = __builtin_bit_cast(f16x2, h);
  return acc + (float)a.x * (float)b.x + (float)a.y * (float)b.y;
#endif
}

__device__ __forceinline__ uint32_t packpair(float x, float y) {
  f16x2 p;
  p.x = (_Float16)x;
  p.y = (_Float16)y;
  return __builtin_bit_cast(uint32_t, p);
}

__device__ __forceinline__ float fsigm(float x) { return 1.f / (1.f + __expf(-x)); }
__device__ __forceinline__ float ftanh(float x) {
  float e = __expf(2.f * x);
  return 1.f - 2.f / (e + 1.f);
}

// ---------------- workspace layout (bytes) ----------------
constexpr size_t ALN(size_t x) { return (x + 1023) & ~(size_t)1023; }
constexpr size_t O_EX    = 0;                       // 4(ld) * 512 * 128 u32 = 1 MB
constexpr size_t SZ_EX   = 4ull * 512 * 128 * 4;
constexpr size_t O_WPK   = ALN(O_EX + SZ_EX);       // 4(ld) * 16chunk * 2048owner * uint4 = 2 MB
constexpr size_t SZ_WPK  = 4ull * 16 * 2048 * 16;
constexpr size_t O_X0    = ALN(O_WPK + SZ_WPK);     // 512 x 125 f32
constexpr size_t SZ_X0   = 512ull * 125 * 4;
constexpr size_t O_WTIH0 = ALN(O_X0 + SZ_X0);       // 2 x [128][1024]
constexpr size_t SZ_WTIH0 = 2ull * 128 * 1024 * 4;
constexpr size_t O_WTIH1 = ALN(O_WTIH0 + SZ_WTIH0); // 2 x [512][1024]
constexpr size_t SZ_WTIH1 = 2ull * 512 * 1024 * 4;
constexpr size_t O_WTA   = ALN(O_WTIH1 + SZ_WTIH1); // [512][100]
constexpr size_t SZ_WTAB = 512ull * 100 * 4;
constexpr size_t O_WTB   = ALN(O_WTA + SZ_WTAB);    // [512][100]
constexpr size_t O_PRE0  = ALN(O_WTB + SZ_WTAB);    // 2 x [512][1024]
constexpr size_t SZ_PRE  = 2ull * 512 * 1024 * 4;
constexpr size_t O_PRE1  = ALN(O_PRE0 + SZ_PRE);
constexpr size_t O_H0    = ALN(O_PRE1 + SZ_PRE);    // [512][512]
constexpr size_t SZ_H    = 512ull * 512 * 4;
constexpr size_t O_H1    = ALN(O_H0 + SZ_H);
constexpr size_t O_AM    = ALN(O_H1 + SZ_H);        // [512][100]
constexpr size_t O_BT    = ALN(O_AM + SZ_WTAB);     // [100][512]

// ---------------- kernels ----------------

// sentinel-fill the h-exchange slots (4*512*128 = 262144 words)
__global__ void k_init_ex(uint32_t* __restrict__ ex) {
  ex[(size_t)blockIdx.x * 256 + threadIdx.x] = SENT;
}

// embeds: x0[i][0:100] = word_emb[wi[i]], x0[i][100:125] = pos_emb[pi[i]]
__global__ void k_embed(const int* __restrict__ wi, const int* __restrict__ pi,
                        const float* __restrict__ we, const float* __restrict__ pe,
                        float* __restrict__ x0) {
  int i = blockIdx.x, k = threadIdx.x;
  if (k < 100)      x0[i * 125 + k] = we[(size_t)wi[i] * 100 + k];
  else if (k < 125) x0[i * 125 + k] = pe[(size_t)pi[i] * 25 + (k - 100)];
}

// dst[k][m] = src[m][colOff+k] for k<colCnt else 0 ; dst dims [dstRows][srcRows]
__global__ void k_transpose(const float* __restrict__ src, int srcRows, int srcCols,
                            int colOff, int colCnt, int dstRows, float* __restrict__ dst) {
  __shared__ float tile[32][33];
  int k0 = blockIdx.x * 32, m0 = blockIdx.y * 32;
  int tx = threadIdx.x, ty = threadIdx.y;
#pragma unroll
  for (int i = 0; i < 4; i++) {
    int m = m0 + ty + i * 8, k = k0 + tx;
    float v = 0.f;
    if (m < srcRows && k < colCnt) v = src[(size_t)m * srcCols + colOff + k];
    tile[ty + i * 8][tx] = v;
  }
  __syncthreads();
#pragma unroll
  for (int i = 0; i < 4; i++) {
    int k = k0 + ty + i * 8, m = m0 + tx;
    if (k < dstRows && m < srcRows) dst[(size_t)k * srcRows + m] = tile[tx][ty + i * 8];
  }
}

// Whh (4 x [1024][256] f32) -> packed f16 pairs, layout [ld][chunk(16)][owner(2048)]
// uint4. Owner o = b*1024 + t; thread t<512 covers k-half = b (own), t>=512
// covers k-half = b^1 (partner). Chunk c covers k = khalf*128 + c*8 .. +7.
__global__ void k_packwhh(const float* __restrict__ whh0, const float* __restrict__ whh1,
                          uint32_t* __restrict__ wpk) {
  int ld = blockIdx.x;                        // layer*2 + dir
  int c  = blockIdx.y;                        // 0..15
  int o  = blockIdx.z * 1024 + threadIdx.x;   // 0..2047
  const float* W = (ld < 2) ? (whh0 + (size_t)ld * 1024 * 256)
                            : (whh1 + (size_t)(ld - 2) * 1024 * 256);
  int b = o >> 10, t = o & 1023;
  int hi = t >> 9, tr = t & 511;
  int gate = tr >> 7, u = tr & 127;
  int R = gate * 256 + b * 128 + u;
  int khalf = hi ? (b ^ 1) : b;
  const float* src = W + (size_t)R * 256 + khalf * 128 + c * 8;
  uint4 outv;
  outv.x = packpair(src[0], src[1]);
  outv.y = packpair(src[2], src[3]);
  outv.z = packpair(src[4], src[5]);
  outv.w = packpair(src[6], src[7]);
  ((uint4*)wpk)[(size_t)ld * 32768 + (size_t)c * 2048 + o] = outv;
}

// out[gr][col] (or transposed) = sum_k X[xr][k] * WT[k][col] + bias1[col]+bias2[col]
// WT is [Kpad][Nn] with rows >= Kreal zero-filled.
__global__ __launch_bounds__(256) void k_gemm(
    const float* __restrict__ X, const float* __restrict__ WT,
    const float* __restrict__ bias1, const float* __restrict__ bias2,
    float* __restrict__ out, int Mm, int Nn, int Kpad, int Kreal, int ldx,
    int flipX, int outT) {
  __shared__ float XS[32][64];
  int tid = threadIdx.x;
  int cl = tid & 63, rg = tid >> 6;
  int col = blockIdx.y * 64 + cl;
  int colr = (col < Nn) ? col : (Nn - 1);
  int row0 = blockIdx.x * 32;
  float acc[8];
#pragma unroll
  for (int r = 0; r < 8; r++) acc[r] = 0.f;
  for (int k0 = 0; k0 < Kpad; k0 += 64) {
#pragma unroll
    for (int ii = 0; ii < 8; ii++) {
      int idx = ii * 256 + tid;
      int r = idx >> 6, kk = idx & 63;
      int gr = row0 + r;
      int xr = flipX ? (Mm - 1 - gr) : gr;
      int k = k0 + kk;
      XS[r][kk] = (k < Kreal) ? X[(size_t)xr * ldx + k] : 0.f;
    }
    __syncthreads();
#pragma unroll 4
    for (int kk = 0; kk < 64; kk++) {
      float w = WT[(size_t)(k0 + kk) * Nn + colr];
#pragma unroll
      for (int r = 0; r < 8; r++) acc[r] += XS[rg * 8 + r][kk] * w;
    }
    __syncthreads();
  }
  if (col < Nn) {
    float bb = (bias1 ? bias1[col] : 0.f) + (bias2 ? bias2[col] : 0.f);
#pragma unroll
    for (int r = 0; r < 8; r++) {
      int gr = row0 + rg * 8 + r;
      float v = acc[r] + bb;
      if (outT) out[(size_t)col * Mm + gr] = v;
      else      out[(size_t)gr * Nn + col] = v;
    }
  }
}

// Recurrent scan. Grid = 4 blocks: (dir = bx>>1, half = bx&1). 1024 threads.
// Thread t: row-part tr = t&511 (gate-row R = (tr>>7)*256 + b*128 + (tr&127)),
// k-half = (t<512 ? own : partner). 16 named uint4 = 64 weight VGPRs/thread.
// amdgpu_waves_per_eu(4,4): exactly one 16-wave workgroup per CU -> 128-VGPR
// allocator budget, no occupancy-chasing spills.
__global__ __launch_bounds__(1024)
__attribute__((amdgpu_waves_per_eu(4, 4)))
void k_lstm(
    const float* __restrict__ preBase, const uint32_t* __restrict__ wpkL,
    float* __restrict__ hout, uint32_t* __restrict__ exL) {
  int d = blockIdx.x >> 1, b = blockIdx.x & 1;
  int t = threadIdx.x;
  int tr = t & 511, hi = t >> 9;
  const float* pre = preBase + (size_t)d * 512 * 1024;
  uint32_t* ex = exL + (size_t)d * 512 * 128;
  const uint4* wv = (const uint4*)(wpkL + (size_t)d * 131072);

  __shared__ __align__(16) uint32_t h2[128];  // packed f16 pairs of full h[256]
  __shared__ __align__(8) float shp[1024];    // partial dots (own: +pre)

  const int o = b * 1024 + t;
  const int khalf = hi ? (b ^ 1) : b;

  // ---- weight prologue: 16 named uint4 = 64 pinned VGPRs ----
#define WLOAD(i) uint4 W##i = wv[(i) * 2048 + o];
  WLOAD(0)  WLOAD(1)  WLOAD(2)  WLOAD(3)  WLOAD(4)  WLOAD(5)  WLOAD(6)  WLOAD(7)
  WLOAD(8)  WLOAD(9)  WLOAD(10) WLOAD(11) WLOAD(12) WLOAD(13) WLOAD(14) WLOAD(15)
#undef WLOAD
#define WPIN(i) asm volatile("" : "+v"(W##i.x), "+v"(W##i.y), "+v"(W##i.z), "+v"(W##i.w));
  WPIN(0)  WPIN(1)  WPIN(2)  WPIN(3)  WPIN(4)  WPIN(5)  WPIN(6)  WPIN(7)
  WPIN(8)  WPIN(9)  WPIN(10) WPIN(11) WPIN(12) WPIN(13) WPIN(14) WPIN(15)
#undef WPIN

  if (t < 128) h2[t] = 0u;
  float c0 = 0.f, c1 = 0.f;  // wave0: cell state for units 2t, 2t+1
  const int gate = tr >> 7, u = tr & 127;
  const int RR = gate * 256 + b * 128 + u;
  float pcur = (t < 512) ? pre[RR] : 0.f;
  __syncthreads();

  for (int s = 0; s < 512; s++) {
    float pnext = (t < 512 && s < 511) ? pre[(size_t)(s + 1) * 1024 + RR] : 0.f;
    // 64-pair half-row dot; a0 seeded with pre (0 for partner-half threads)
    float a0 = pcur, a1 = 0.f, a2 = 0.f, a3 = 0.f;
    const uint4* hb = ((const uint4*)h2) + khalf * 16;
#define DOT(i) { uint4 hv = hb[i];                 \
      a0 = fdot2f(W##i.x, hv.x, a0);               \
      a1 = fdot2f(W##i.y, hv.y, a1);               \
      a2 = fdot2f(W##i.z, hv.z, a2);               \
      a3 = fdot2f(W##i.w, hv.w, a3); }
    DOT(0)  DOT(1)  DOT(2)  DOT(3)  DOT(4)  DOT(5)  DOT(6)  DOT(7)
    DOT(8)  DOT(9)  DOT(10) DOT(11) DOT(12) DOT(13) DOT(14) DOT(15)
#undef DOT
    shp[t] = (a0 + a1) + (a2 + a3);
    __syncthreads();
    if (t < 64) {
      // units (2t, 2t+1): sum own+partner halves; shp float2 view:
      // gate g units (2t,2t+1) -> SP2[g*64+t] (own) + SP2[256+g*64+t] (partner)
      const float2* SP2 = (const float2*)shp;
      float2 giA = SP2[t],       giB = SP2[256 + t];
      float2 gfA = SP2[64 + t],  gfB = SP2[320 + t];
      float2 ggA = SP2[128 + t], ggB = SP2[384 + t];
      float2 goA = SP2[192 + t], goB = SP2[448 + t];
      float gi0 = giA.x + giB.x, gi1 = giA.y + giB.y;
      float gf0 = gfA.x + gfB.x, gf1 = gfA.y + gfB.y;
      float gg0 = ggA.x + ggB.x, gg1 = ggA.y + ggB.y;
      float go0 = goA.x + goB.x, go1 = goA.y + goB.y;
      c0 = fsigm(gf0) * c0 + fsigm(gi0) * ftanh(gg0);
      c1 = fsigm(gf1) * c1 + fsigm(gi1) * ftanh(gg1);
      float hA = fsigm(go0) * ftanh(c0);
      float hB = fsigm(go1) * ftanh(c1);
      uint32_t pk = packpair(hA, hB);
      // publish to partner FIRST (critical path), then local stores
      __hip_atomic_store(&ex[(size_t)s * 128 + b * 64 + t], pk,
                         __ATOMIC_RELAXED, SCOPE_AGENT);
      h2[b * 64 + t] = pk;
      int pos = (d == 0) ? s : (511 - s);
      *(float2*)&hout[(size_t)pos * 512 + d * 256 + b * 128 + 2 * t] =
          make_float2(hA, hB);
    } else if (t < 128) {
      // wave1: poll partner half (overlaps wave0's transcendentals)
      int tt = t - 64;
      uint32_t q;
      do {
        q = __hip_atomic_load(&ex[(size_t)s * 128 + (b ^ 1) * 64 + tt],
                              __ATOMIC_RELAXED, SCOPE_AGENT);
      } while (__any(q == SENT));
      h2[(b ^ 1) * 64 + tt] = q;
    }
    pcur = pnext;
    __syncthreads();
  }
}

// scores[i][j] = b2 + sum_m W2[m] * tanh(a[i][m] + bT[m][j])   (b1 folded into a)
__global__ __launch_bounds__(512) void k_score(
    const float* __restrict__ am, const float* __restrict__ bT,
    const float* __restrict__ W2, const float* __restrict__ b2,
    float* __restrict__ out) {
  int i = blockIdx.x;
  int j = threadIdx.x;
  __shared__ float aL[100], w2L[100];
  if (j < 100) { aL[j] = am[(size_t)i * 100 + j]; w2L[j] = W2[j]; }
  __syncthreads();
  float acc = b2[0];
#pragma unroll 4
  for (int m = 0; m < 100; m++)
    acc += w2L[m] * ftanh(aL[m] + bT[(size_t)m * 512 + j]);
  out[(size_t)i * 512 + j] = acc;
}

// ---------------- launch ----------------
extern "C" void kernel_launch(void* const* d_in, const int* in_sizes, int n_in,
                              void* d_out, int out_size, void* d_ws, size_t ws_size,
                              hipStream_t stream) {
  const int*   wi   = (const int*)d_in[0];
  const int*   pi   = (const int*)d_in[1];
  const float* we   = (const float*)d_in[2];
  const float* pe   = (const float*)d_in[3];
  const float* Wih0 = (const float*)d_in[4];
  const float* Whh0 = (const float*)d_in[5];
  const float* bih0 = (const float*)d_in[6];
  const float* bhh0 = (const float*)d_in[7];
  const float* Wih1 = (const float*)d_in[8];
  const float* Whh1 = (const float*)d_in[9];
  const float* bih1 = (const float*)d_in[10];
  const float* bhh1 = (const float*)d_in[11];
  const float* W1   = (const float*)d_in[12];
  const float* b1   = (const float*)d_in[13];
  const float* W2   = (const float*)d_in[14];
  const float* b2   = (const float*)d_in[15];

  char* ws = (char*)d_ws;
  uint32_t* ex    = (uint32_t*)(ws + O_EX);
  uint32_t* wpk   = (uint32_t*)(ws + O_WPK);
  float* x0    = (float*)(ws + O_X0);
  float* wtih0 = (float*)(ws + O_WTIH0);
  float* wtih1 = (float*)(ws + O_WTIH1);
  float* wta   = (float*)(ws + O_WTA);
  float* wtb   = (float*)(ws + O_WTB);
  float* pre0  = (float*)(ws + O_PRE0);
  float* pre1  = (float*)(ws + O_PRE1);
  float* h0    = (float*)(ws + O_H0);
  float* h1    = (float*)(ws + O_H1);
  float* am    = (float*)(ws + O_AM);
  float* bt    = (float*)(ws + O_BT);
  float* out   = (float*)d_out;

  k_init_ex<<<1024, 256, 0, stream>>>(ex);  // 262144 words

  k_embed<<<512, 128, 0, stream>>>(wi, pi, we, pe, x0);

  dim3 tb(32, 8);
  k_transpose<<<dim3(4, 32),  tb, 0, stream>>>(Wih0,              1024, 125, 0,   125, 128, wtih0);
  k_transpose<<<dim3(4, 32),  tb, 0, stream>>>(Wih0 + 1024 * 125, 1024, 125, 0,   125, 128, wtih0 + 128 * 1024);
  k_transpose<<<dim3(16, 32), tb, 0, stream>>>(Wih1,              1024, 512, 0,   512, 512, wtih1);
  k_transpose<<<dim3(16, 32), tb, 0, stream>>>(Wih1 + 1024 * 512, 1024, 512, 0,   512, 512, wtih1 + 512 * 1024);
  k_transpose<<<dim3(16, 4),  tb, 0, stream>>>(W1,                100, 1024, 0,   512, 512, wta);
  k_transpose<<<dim3(16, 4),  tb, 0, stream>>>(W1,                100, 1024, 512, 512, 512, wtb);

  k_packwhh<<<dim3(4, 16, 2), 1024, 0, stream>>>(Whh0, Whh1, wpk);

  for (int d = 0; d < 2; d++)
    k_gemm<<<dim3(16, 16), 256, 0, stream>>>(x0, wtih0 + (size_t)d * 128 * 1024,
        bih0 + d * 1024, bhh0 + d * 1024, pre0 + (size_t)d * 512 * 1024,
        512, 1024, 128, 125, 125, d, 0);

  k_lstm<<<4, 1024, 0, stream>>>(pre0, wpk, h0, ex);

  for (int d = 0; d < 2; d++)
    k_gemm<<<dim3(16, 16), 256, 0, stream>>>(h0, wtih1 + (size_t)d * 512 * 1024,
        bih1 + d * 1024, bhh1 + d * 1024, pre1 + (size_t)d * 512 * 1024,
        512, 1024, 512, 512, 512, d, 0);

  k_lstm<<<4, 1024, 0, stream>>>(pre1, wpk + 2 * 131072, h1, ex + 2ull * 512 * 128);

  k_gemm<<<dim3(16, 2), 256, 0, stream>>>(h1, wta, b1, nullptr, am, 512, 100, 512, 512, 512, 0, 0);
  k_gemm<<<dim3(16, 2), 256, 0, stream>>>(h1, wtb, nullptr, nullptr, bt, 512, 100, 512, 512, 512, 0, 1);

  k_score<<<512, 512, 0, stream>>>(am, bt, W2, b2, out);
}